// Round 6
// baseline (49920.468 us; speedup 1.0000x reference)
//
#include <hip/hip_runtime.h>

constexpr int NB = 32;    // batch
constexpr int NT = 128;   // time
constexpr int NE = 256;   // embed
constexpr int NH = 256;   // hidden
constexpr int NC = 16;    // classes

typedef _Float16 f16;
typedef f16 f16x2 __attribute__((ext_vector_type(2)));
typedef f16 f16x8 __attribute__((ext_vector_type(8)));

__device__ __forceinline__ float sigmoidf_(float x) {
    return 1.f / (1.f + __expf(-x));
}
__device__ __forceinline__ float tanhf_(float x) {
    x = fminf(fmaxf(x, -15.f), 15.f);
    float e = __expf(-2.f * x);
    return (1.f - e) / (1.f + e);
}
__device__ __forceinline__ float dot4_(float4 a, float4 b) {
    return a.x * b.x + a.y * b.y + a.z * b.z + a.w * b.w;
}
#if __has_builtin(__builtin_amdgcn_fdot2)
__device__ __forceinline__ float fdot2_(f16x2 a, f16x2 b, float c) {
    return __builtin_amdgcn_fdot2(a, b, c, false);
}
#else
__device__ __forceinline__ float fdot2_(f16x2 a, f16x2 b, float c) {
    return (float)a[0] * (float)b[0] + (float)a[1] * (float)b[1] + c;
}
#endif
#define PAIR(v, k) __builtin_shufflevector((v), (v), (k), (k) + 1)

// ---------------- Prologue 1: xp[t][b][j] = x[b][t][:] . W_in[j][:] + b_in[j]
__global__ __launch_bounds__(256) void k_lin_in(
    const float* __restrict__ x, const float* __restrict__ W_in,
    const float* __restrict__ b_in, float* __restrict__ xp) {
    const int tb = blockIdx.x;           // t*NB + b
    const int t = tb >> 5, b = tb & 31;
    const int tid = threadIdx.x;
    __shared__ __align__(16) float xl[NE];
    xl[tid] = x[(b * NT + t) * NE + tid];
    __syncthreads();
    const float* __restrict__ wr = W_in + tid * NE;
    float acc = b_in[tid];
#pragma unroll 8
    for (int k = 0; k < NE; k += 4)
        acc += dot4_(*(const float4*)(wr + k), *(const float4*)(xl + k));
    xp[tb * NH + tid] = acc;
}

// ---------------- Prologue 2: xw = xp.Wih^T + bih ; uax = xp.Ua^T + ub
__global__ __launch_bounds__(256) void k_proj(
    const float* __restrict__ xp, const float* __restrict__ Wih,
    const float* __restrict__ bih, const float* __restrict__ Ua,
    const float* __restrict__ ub, float* __restrict__ xw,
    float* __restrict__ uax) {
    const int tb = blockIdx.x;
    const int tid = threadIdx.x;
    __shared__ __align__(16) float xl[NH];
    xl[tid] = xp[tb * NH + tid];
    __syncthreads();
    const float* __restrict__ wr = Wih + tid * NH;
    const float* __restrict__ wz = Wih + (NH + tid) * NH;
    const float* __restrict__ wn = Wih + (2 * NH + tid) * NH;
    const float* __restrict__ wu = Ua + tid * NH;
    float ar = bih[tid], az = bih[NH + tid], an = bih[2 * NH + tid], au = ub[tid];
#pragma unroll 4
    for (int k = 0; k < NH; k += 4) {
        float4 xv = *(const float4*)(xl + k);
        ar += dot4_(*(const float4*)(wr + k), xv);
        az += dot4_(*(const float4*)(wz + k), xv);
        an += dot4_(*(const float4*)(wn + k), xv);
        au += dot4_(*(const float4*)(wu + k), xv);
    }
    float* xwp = xw + tb * (3 * NH);
    xwp[tid] = ar;
    xwp[NH + tid] = az;
    xwp[2 * NH + tid] = an;
    uax[tb * NH + tid] = au;
}

// ---------------- Pack Whh/Wa to f16x8 [kc][row] so streamed loads coalesce.
__global__ __launch_bounds__(256) void k_pack(
    const float* __restrict__ Whh, const float* __restrict__ Wa,
    f16x8* __restrict__ Wpk, f16x8* __restrict__ Wak) {
    const int id = blockIdx.x * 256 + threadIdx.x;
    if (id < 32 * 768) {
        const int kc = id / 768, row = id % 768;
        const float* src = Whh + row * NH + kc * 8;
        f16x8 v;
#pragma unroll
        for (int m = 0; m < 8; ++m) v[m] = (f16)src[m];
        Wpk[id] = v;
    } else {
        const int id2 = id - 32 * 768;   // < 8192
        const int kc = id2 >> 8, row = id2 & 255;
        const float* src = Wa + row * NH + kc * 8;
        f16x8 v;
#pragma unroll
        for (int m = 0; m < 8; ++m) v[m] = (f16)src[m];
        Wak[id2] = v;
    }
}

// ---------------- Phase 1: sequential carried-hidden chain. 1 WG / batch.
// ROUND 4 POST-MORTEM: VGPR stuck at 128 for (512,2)/(512,1)/waves_per_eu --
// allocator provisions 131072/(2*threads) regs/thread no matter what. The
// 192-reg resident weight set can NEVER fit -> ~100 regs spilled; step time
// was scratch-reload-bound (bank-conflict fix changed nothing: 9.56->9.63ms).
// ROUND 5: STREAM the weights from L2 instead of keeping them resident.
// Wpk (f16x8 [kc][768rows], 384KB) is L2-resident & shared by all 32 blocks.
// Per step each thread loads its 48 x 16B chunks (coalesced 512B bursts per
// half-wave); the unrolled chunk loop lets the scheduler pipeline L2 latency
// under the fdot2 chain. Per-lane regs: in-flight window + working set < 128
// -> no spill. The base pointer is laundered with empty asm each step so
// LICM can't hoist the (loop-invariant) weight loads back into registers.
__global__ __launch_bounds__(512) void k_chain(
    const f16x8* __restrict__ Wpk, const float* __restrict__ bhh,
    const float* __restrict__ xw, float* __restrict__ Hc) {
    const int b = blockIdx.x;
    const int tid = threadIdx.x;
    const int j = tid >> 1, c = tid & 1;
    // padded h buffer: element k at [k] for k<128, [136+(k-128)] for k>=128.
    // c=0 reads banks 4s..4s+3, c=1 reads (4s+4..4s+7)%32 -> conflict-free
    // (verified r4: SQ_LDS_BANK_CONFLICT 1.35e8 -> 0).
    __shared__ __align__(16) f16 hb[2][272];

    const float bhr = bhh[j], bhz = bhh[NH + j], bhn = bhh[2 * NH + j];
    if (tid < NH) {
        const int idx = (tid < 128) ? tid : 136 + (tid - 128);
        hb[0][idx] = (f16)0.f;
    }
    float hprev = 0.f;
    int cur = 0;
    const int jpad = (j < 128) ? j : 136 + (j - 128);   // padded write index
    // this thread's weight region: rows {j, 256+j, 512+j}, kc = c*16 + s
    const f16x8* __restrict__ wbase = Wpk + (size_t)(c * 16) * 768 + j;
    // prefetch of the (i=0,t=0) xw row
    const float* __restrict__ x0 = xw + (size_t)b * (3 * NH);
    float xr = x0[j], xz = x0[NH + j], xn = x0[2 * NH + j];
    __syncthreads();

#pragma unroll 1
    for (int i = 0; i < NT; ++i) {
#pragma unroll 1
        for (int t = 0; t <= i; ++t) {
            // opaque zero offset: blocks LICM of the weight loads across steps
            int woff = 0;
            asm volatile("" : "+v"(woff));
            const f16x8* __restrict__ wp =
                (const f16x8*)((const char*)wbase + woff);

            // issue next-step xw loads now; consumed next iteration
            const int t_next = (t == i) ? 0 : t + 1;   // wrap -> (i+1, 0)
            const float* __restrict__ xq = xw + (size_t)(t_next * NB + b) * (3 * NH);
            const float xrn = xq[j], xzn = xq[NH + j], xnn = xq[2 * NH + j];

            const f16* hc = hb[cur] + c * 136;
            float ar = 0.f, az = 0.f, an = 0.f;
#pragma unroll
            for (int s = 0; s < 16; ++s) {
                const f16x8 wR = wp[(size_t)s * 768];
                const f16x8 wZ = wp[(size_t)s * 768 + 256];
                const f16x8 wN = wp[(size_t)s * 768 + 512];
                const f16x8 hv = *(const f16x8*)(hc + s * 8);
                const f16x2 h0 = PAIR(hv, 0), h1 = PAIR(hv, 2),
                            h2 = PAIR(hv, 4), h3 = PAIR(hv, 6);
                ar = fdot2_(PAIR(wR, 0), h0, ar);
                ar = fdot2_(PAIR(wR, 2), h1, ar);
                ar = fdot2_(PAIR(wR, 4), h2, ar);
                ar = fdot2_(PAIR(wR, 6), h3, ar);
                az = fdot2_(PAIR(wZ, 0), h0, az);
                az = fdot2_(PAIR(wZ, 2), h1, az);
                az = fdot2_(PAIR(wZ, 4), h2, az);
                az = fdot2_(PAIR(wZ, 6), h3, az);
                an = fdot2_(PAIR(wN, 0), h0, an);
                an = fdot2_(PAIR(wN, 2), h1, an);
                an = fdot2_(PAIR(wN, 4), h2, an);
                an = fdot2_(PAIR(wN, 6), h3, an);
            }
            ar += __shfl_xor(ar, 1);
            az += __shfl_xor(az, 1);
            an += __shfl_xor(an, 1);
            const float r = sigmoidf_(xr + ar + bhr);
            const float z = sigmoidf_(xz + az + bhz);
            const float n = tanhf_(xn + r * (an + bhn));
            const float hnew = (1.f - z) * n + z * hprev;
            hprev = hnew;
            if (c == 0) {
                hb[cur ^ 1][jpad] = (f16)hnew;
                if (t == i) Hc[((size_t)i * NB + b) * NH + j] = hnew;
            }
            xr = xrn; xz = xzn; xn = xnn;
            cur ^= 1;
            __syncthreads();
        }
    }
}

// ---------------- Phase 2: lockstep re-run of all prefix chains + fused attention.
// Grid: 32 b x 8 bk; each WG owns 16 chains i = bk + 8u, 512 threads:
// col = tid>>1 (0..255), c = tid&1 (128-wide k-half). 8 waves = 2 waves/SIMD.
__global__ __attribute__((amdgpu_waves_per_eu(2, 2))) __launch_bounds__(512)
void k_attn(
    const float* __restrict__ Hc, const float* __restrict__ xw,
    const float* __restrict__ uax, const float* __restrict__ xp,
    const f16x8* __restrict__ Wpk, const f16x8* __restrict__ Wak,
    const float* __restrict__ bhh, const float* __restrict__ ba,
    const float* __restrict__ va_w, const float* __restrict__ Wo,
    const float* __restrict__ bo, float* __restrict__ out) {
    const int b  = blockIdx.x >> 3;
    const int bk = blockIdx.x & 7;
    const int tid = threadIdx.x;
    const int col = tid >> 1, c = tid & 1;
    const int lane = tid & 63, wid = tid >> 6;

    __shared__ __align__(16) float S[16][NH];
    __shared__ __align__(16) f16 Sh[16][NH];
    __shared__ float red1[8][16];
    __shared__ float mL[16], lL[16], aL[16], eL[16];
    __shared__ float redH[8][256];

    const float bhr = bhh[col], bhz = bhh[NH + col], bhn = bhh[2 * NH + col];
    const float ba_j = ba[col], va_j = va_w[col];
    float ctx[16];
#pragma unroll
    for (int u = 0; u < 16; ++u) {
        const int ic = bk + 8 * u;
        const float hv = (ic == 0) ? 0.f : Hc[((size_t)(ic - 1) * NB + b) * NH + col];
        if (c == 0) { S[u][col] = hv; Sh[u][col] = (f16)hv; }
        ctx[u] = 0.f;
    }
    if (tid < 16) { mL[tid] = -1e30f; lL[tid] = 0.f; }
    __syncthreads();

    const int imax = bk + 8 * 15;
#pragma unroll 1
    for (int t = 0; t <= imax; ++t) {
        const size_t base = (size_t)(t * NB + b);
        const float xr = xw[base * 3 * NH + col];
        const float xz = xw[base * 3 * NH + NH + col];
        const float xn = xw[base * 3 * NH + 2 * NH + col];
        const float ux = uax[base * NH + col];
        const float xpt = xp[base * NH + col];

        // ---- GRU matvec for active chains (i >= t); k-half per c
        float ar[16], az[16], an[16];
#pragma unroll
        for (int u = 0; u < 16; ++u) { ar[u] = 0.f; az[u] = 0.f; an[u] = 0.f; }
#pragma unroll 2
        for (int kk = 0; kk < 16; ++kk) {
            const int kc = kk * 2 + c;
            const f16x8 wR = Wpk[kc * 768 + col];
            const f16x8 wZ = Wpk[kc * 768 + 256 + col];
            const f16x8 wN = Wpk[kc * 768 + 512 + col];
#pragma unroll
            for (int u = 0; u < 16; ++u) {
                if (bk + 8 * u < t) continue;      // frozen chain (uniform branch)
                const f16x8 hv = *(const f16x8*)&Sh[u][kc * 8];
                const f16x2 h0 = PAIR(hv, 0), h1 = PAIR(hv, 2),
                            h2 = PAIR(hv, 4), h3 = PAIR(hv, 6);
                ar[u] = fdot2_(PAIR(wR, 0), h0, ar[u]);
                ar[u] = fdot2_(PAIR(wR, 2), h1, ar[u]);
                ar[u] = fdot2_(PAIR(wR, 4), h2, ar[u]);
                ar[u] = fdot2_(PAIR(wR, 6), h3, ar[u]);
                az[u] = fdot2_(PAIR(wZ, 0), h0, az[u]);
                az[u] = fdot2_(PAIR(wZ, 2), h1, az[u]);
                az[u] = fdot2_(PAIR(wZ, 4), h2, az[u]);
                az[u] = fdot2_(PAIR(wZ, 6), h3, az[u]);
                an[u] = fdot2_(PAIR(wN, 0), h0, an[u]);
                an[u] = fdot2_(PAIR(wN, 2), h1, an[u]);
                an[u] = fdot2_(PAIR(wN, 4), h2, an[u]);
                an[u] = fdot2_(PAIR(wN, 6), h3, an[u]);
            }
        }
        float hn[16];
#pragma unroll
        for (int u = 0; u < 16; ++u) {
            if (bk + 8 * u < t) continue;
            float arf = ar[u] + __shfl_xor(ar[u], 1);
            float azf = az[u] + __shfl_xor(az[u], 1);
            float anf = an[u] + __shfl_xor(an[u], 1);
            const float r = sigmoidf_(xr + arf + bhr);
            const float z = sigmoidf_(xz + azf + bhz);
            const float n = tanhf_(xn + r * (anf + bhn));
            hn[u] = (1.f - z) * n + z * S[u][col];
        }
        __syncthreads();                      // all Sh reads of this step done
#pragma unroll
        for (int u = 0; u < 16; ++u) {
            if (bk + 8 * u < t) continue;
            if (c == 0) { S[u][col] = hn[u]; Sh[u][col] = (f16)hn[u]; }
        }
        __syncthreads();                      // Sh now holds outs[t]

        // ---- attention scores for active chains
        float sc[16];
#pragma unroll
        for (int u = 0; u < 16; ++u) sc[u] = 0.f;
#pragma unroll 2
        for (int kk = 0; kk < 16; ++kk) {
            const int kc = kk * 2 + c;
            const f16x8 wA = Wak[kc * 256 + col];
#pragma unroll
            for (int u = 0; u < 16; ++u) {
                if (bk + 8 * u < t) continue;
                const f16x8 hv = *(const f16x8*)&Sh[u][kc * 8];
                sc[u] = fdot2_(PAIR(wA, 0), PAIR(hv, 0), sc[u]);
                sc[u] = fdot2_(PAIR(wA, 2), PAIR(hv, 2), sc[u]);
                sc[u] = fdot2_(PAIR(wA, 4), PAIR(hv, 4), sc[u]);
                sc[u] = fdot2_(PAIR(wA, 6), PAIR(hv, 6), sc[u]);
            }
        }
#pragma unroll
        for (int u = 0; u < 16; ++u) {
            if (bk + 8 * u < t) continue;
            const float sv = sc[u] + __shfl_xor(sc[u], 1);   // full-k (Wa h)[col]
            float p = (c == 0) ? va_j * tanhf_(sv + ba_j + ux) : 0.f;
#pragma unroll
            for (int off = 32; off; off >>= 1) p += __shfl_xor(p, off);
            if (lane == 0) red1[wid][u] = p;
        }
        __syncthreads();
        if (tid < 16 && bk + 8 * tid >= t) {   // online softmax state per chain
            float s = 0.f;
#pragma unroll
            for (int w = 0; w < 8; ++w) s += red1[w][tid];
            const float mo = mL[tid];
            const float mn = fmaxf(mo, s);
            const float e  = __expf(s - mn);
            const float al = __expf(mo - mn);
            lL[tid] = lL[tid] * al + e;
            mL[tid] = mn; aL[tid] = al; eL[tid] = e;
        }
        __syncthreads();
#pragma unroll
        for (int u = 0; u < 16; ++u) {
            if (bk + 8 * u < t) continue;
            ctx[u] = ctx[u] * aL[u] + eL[u] * xpt;
        }
    }

    // ---- output head per chain: logits = [h_last, context] @ Wo^T + bo
#pragma unroll 1
    for (int u = 0; u < 16; ++u) {
        const float hl = S[u][col];           // final state == h_last(i)
        const float cx = ctx[u] / lL[u];
#pragma unroll
        for (int cls = 0; cls < NC; ++cls) {
            float p = Wo[cls * (2 * NH) + col] * hl + Wo[cls * (2 * NH) + NH + col] * cx;
            p = (c == 0) ? p : 0.f;
#pragma unroll
            for (int off = 32; off; off >>= 1) p += __shfl_xor(p, off);
            if (lane == 0) redH[wid][u * 16 + cls] = p;
        }
    }
    __syncthreads();
    if (tid < 256) {
        const int u = tid >> 4, cls = tid & 15;
        const int ic = bk + 8 * u;
        float lg = bo[cls];
#pragma unroll
        for (int w = 0; w < 8; ++w) lg += redH[w][tid];
        out[((size_t)b * NT + ic) * NC + cls] = sigmoidf_(lg);
    }
}

extern "C" void kernel_launch(void* const* d_in, const int* in_sizes, int n_in,
                              void* d_out, int out_size, void* d_ws, size_t ws_size,
                              hipStream_t stream) {
    (void)in_sizes; (void)n_in; (void)out_size; (void)ws_size;
    const float* x    = (const float*)d_in[0];
    const float* W_in = (const float*)d_in[1];
    const float* b_in = (const float*)d_in[2];
    const float* Wih  = (const float*)d_in[3];
    const float* bih  = (const float*)d_in[4];
    const float* Whh  = (const float*)d_in[5];
    const float* bhh  = (const float*)d_in[6];
    const float* Wa   = (const float*)d_in[7];
    const float* ba   = (const float*)d_in[8];
    const float* Ua   = (const float*)d_in[9];
    const float* ub   = (const float*)d_in[10];
    const float* va_w = (const float*)d_in[11];
    // d_in[12] = va_b: cancels in softmax
    const float* Wo   = (const float*)d_in[13];
    const float* bo   = (const float*)d_in[14];
    float* out = (float*)d_out;

    float* ws  = (float*)d_ws;
    float* xp  = ws;                                    // NT*NB*NH        (4 MB)
    float* xw  = xp  + (size_t)NT * NB * NH;            // NT*NB*3NH       (12.6 MB)
    float* uax = xw  + (size_t)NT * NB * 3 * NH;        // NT*NB*NH        (4 MB)
    float* Hc  = uax + (size_t)NT * NB * NH;            // NT*NB*NH        (4 MB)
    f16x8* Wpk = (f16x8*)(Hc + (size_t)NT * NB * NH);   // 32*768 f16x8    (384 KB)
    f16x8* Wak = Wpk + 32 * 768;                        // 32*256 f16x8    (128 KB)

    hipLaunchKernelGGL(k_lin_in, dim3(NT * NB), dim3(256), 0, stream, x, W_in, b_in, xp);
    hipLaunchKernelGGL(k_proj,   dim3(NT * NB), dim3(256), 0, stream, xp, Wih, bih, Ua, ub, xw, uax);
    hipLaunchKernelGGL(k_pack,   dim3(128),     dim3(256), 0, stream, Whh, Wa, Wpk, Wak);
    hipLaunchKernelGGL(k_chain,  dim3(NB),      dim3(512), 0, stream, Wpk, bhh, xw, Hc);
    hipLaunchKernelGGL(k_attn,   dim3(NB * 8),  dim3(512), 0, stream,
                       Hc, xw, uax, xp, Wpk, Wak, bhh, ba, va_w, Wo, bo, out);
}

// Round 7
// 14940.125 us; speedup vs baseline: 3.3414x; 3.3414x over previous
//
#include <hip/hip_runtime.h>

constexpr int NB = 32;    // batch
constexpr int NT = 128;   // time
constexpr int NE = 256;   // embed
constexpr int NH = 256;   // hidden
constexpr int NC = 16;    // classes

typedef _Float16 f16;
typedef f16 f16x2 __attribute__((ext_vector_type(2)));
typedef f16 f16x8 __attribute__((ext_vector_type(8)));

__device__ __forceinline__ float sigmoidf_(float x) {
    return 1.f / (1.f + __expf(-x));
}
__device__ __forceinline__ float tanhf_(float x) {
    x = fminf(fmaxf(x, -15.f), 15.f);
    float e = __expf(-2.f * x);
    return (1.f - e) / (1.f + e);
}
__device__ __forceinline__ float dot4_(float4 a, float4 b) {
    return a.x * b.x + a.y * b.y + a.z * b.z + a.w * b.w;
}
#if __has_builtin(__builtin_amdgcn_fdot2)
__device__ __forceinline__ float fdot2_(f16x2 a, f16x2 b, float c) {
    return __builtin_amdgcn_fdot2(a, b, c, false);
}
#else
__device__ __forceinline__ float fdot2_(f16x2 a, f16x2 b, float c) {
    return (float)a[0] * (float)b[0] + (float)a[1] * (float)b[1] + c;
}
#endif
#define PAIR(v, k) __builtin_shufflevector((v), (v), (k), (k) + 1)

// ---------------- Prologue 1: xp[t][b][j] = x[b][t][:] . W_in[j][:] + b_in[j]
__global__ __launch_bounds__(256) void k_lin_in(
    const float* __restrict__ x, const float* __restrict__ W_in,
    const float* __restrict__ b_in, float* __restrict__ xp) {
    const int tb = blockIdx.x;           // t*NB + b
    const int t = tb >> 5, b = tb & 31;
    const int tid = threadIdx.x;
    __shared__ __align__(16) float xl[NE];
    xl[tid] = x[(b * NT + t) * NE + tid];
    __syncthreads();
    const float* __restrict__ wr = W_in + tid * NE;
    float acc = b_in[tid];
#pragma unroll 8
    for (int k = 0; k < NE; k += 4)
        acc += dot4_(*(const float4*)(wr + k), *(const float4*)(xl + k));
    xp[tb * NH + tid] = acc;
}

// ---------------- Prologue 2: xw = xp.Wih^T + bih ; uax = xp.Ua^T + ub
__global__ __launch_bounds__(256) void k_proj(
    const float* __restrict__ xp, const float* __restrict__ Wih,
    const float* __restrict__ bih, const float* __restrict__ Ua,
    const float* __restrict__ ub, float* __restrict__ xw,
    float* __restrict__ uax) {
    const int tb = blockIdx.x;
    const int tid = threadIdx.x;
    __shared__ __align__(16) float xl[NH];
    xl[tid] = xp[tb * NH + tid];
    __syncthreads();
    const float* __restrict__ wr = Wih + tid * NH;
    const float* __restrict__ wz = Wih + (NH + tid) * NH;
    const float* __restrict__ wn = Wih + (2 * NH + tid) * NH;
    const float* __restrict__ wu = Ua + tid * NH;
    float ar = bih[tid], az = bih[NH + tid], an = bih[2 * NH + tid], au = ub[tid];
#pragma unroll 4
    for (int k = 0; k < NH; k += 4) {
        float4 xv = *(const float4*)(xl + k);
        ar += dot4_(*(const float4*)(wr + k), xv);
        az += dot4_(*(const float4*)(wz + k), xv);
        an += dot4_(*(const float4*)(wn + k), xv);
        au += dot4_(*(const float4*)(wu + k), xv);
    }
    float* xwp = xw + tb * (3 * NH);
    xwp[tid] = ar;
    xwp[NH + tid] = az;
    xwp[2 * NH + tid] = an;
    uax[tb * NH + tid] = au;
}

// ---------------- Pack Whh/Wa to f16x8 [kc][row] so loads coalesce.
__global__ __launch_bounds__(256) void k_pack(
    const float* __restrict__ Whh, const float* __restrict__ Wa,
    f16x8* __restrict__ Wpk, f16x8* __restrict__ Wak) {
    const int id = blockIdx.x * 256 + threadIdx.x;
    if (id < 32 * 768) {
        const int kc = id / 768, row = id % 768;
        const float* src = Whh + row * NH + kc * 8;
        f16x8 v;
#pragma unroll
        for (int m = 0; m < 8; ++m) v[m] = (f16)src[m];
        Wpk[id] = v;
    } else {
        const int id2 = id - 32 * 768;   // < 8192
        const int kc = id2 >> 8, row = id2 & 255;
        const float* src = Wa + row * NH + kc * 8;
        f16x8 v;
#pragma unroll
        for (int m = 0; m < 8; ++m) v[m] = (f16)src[m];
        Wak[id2] = v;
    }
}

// ---------------- Phase 1: sequential carried-hidden chain. 1 WG / batch.
// LEDGER (r1-r6): VGPR budget is pinned at 65536/threads (64@1024t, 128@512t)
// regardless of launch_bounds arg2 / waves_per_eu -> the 192-reg full weight
// set can never be resident (r2-r4: ~104 regs spilled, 2740 cyc/step).
// Streaming all weights from L2 serialized (r6: VGPR 32, 8900 cyc/step).
// ROUND 7: split weights across ALL THREE pools --
//   r,z gates -> registers (128 f16x8-halves attempted; worst case ~25 spill)
//   n gate    -> LDS (exactly 128 KB; ds_read_b128 per chunk, ~2-way
//                bank aliasing = free per m136; 512 cyc/step LDS BW,
//                overlapped under 768 cyc VALU)
//   h         -> LDS padded layout (r4-verified conflict-free)
// Side bet: 132 KB LDS forces 1 WG/CU; if the compiler derives the VGPR
// budget from LDS-limited occupancy, the cap rises to 256 -> zero spill.
// VGPR_Count in the profile adjudicates.
__global__ __launch_bounds__(512) void k_chain(
    const f16x8* __restrict__ Wpk, const float* __restrict__ bhh,
    const float* __restrict__ xw, float* __restrict__ Hc) {
    const int b = blockIdx.x;
    const int tid = threadIdx.x;
    const int j = tid >> 1, c = tid & 1;

    __shared__ __align__(16) f16x8 nW[32 * 256];   // 128 KB: [kc][row]
    __shared__ __align__(16) f16 hb[2][272];       // padded: k<128 at [k], else [136+k-128]

    // stage n-gate (Wpk rows 512..767) into LDS, coalesced 16B per lane
#pragma unroll
    for (int it = 0; it < 16; ++it) {
        const int id = it * 512 + tid;             // kc = id>>8, row = id&255
        nW[id] = Wpk[(size_t)(id >> 8) * 768 + 512 + (id & 255)];
    }

    // resident r,z weights: 32 x f16x8 (128 VGPRs attempted)
    f16x8 rw[16], zw[16];
    {
        const f16x8* __restrict__ rbase = Wpk + (size_t)(c * 16) * 768 + j;
#pragma unroll
        for (int s = 0; s < 16; ++s) {
            rw[s] = rbase[(size_t)s * 768];        // r rows: 0..255
            zw[s] = rbase[(size_t)s * 768 + 256];  // z rows: 256..511
        }
    }
    const float bhr = bhh[j], bhz = bhh[NH + j], bhn = bhh[2 * NH + j];
    if (tid < NH) hb[0][(tid < 128) ? tid : 136 + (tid - 128)] = (f16)0.f;
    float hprev = 0.f;
    int cur = 0;
    const int jpad = (j < 128) ? j : 136 + (j - 128);
    // this thread's n-gate slice in LDS: chunk (c*16+s), row j
    const f16* __restrict__ nbase = (const f16*)(nW + (c * 16) * 256 + j);
    __syncthreads();

#pragma unroll 1
    for (int i = 0; i < NT; ++i) {
#pragma unroll 1
        for (int t = 0; t <= i; ++t) {
            // xw loads issued at step top, consumed ~800 cyc later (post-dots)
            const float* __restrict__ xwp = xw + (size_t)(t * NB + b) * (3 * NH);
            const float xr = xwp[j], xz = xwp[NH + j], xn = xwp[2 * NH + j];

            const f16* hc = hb[cur] + c * 136;
            float ar = 0.f, az = 0.f, an = 0.f;
#pragma unroll
            for (int s = 0; s < 16; ++s) {
                const f16x8 hv = *(const f16x8*)(hc + s * 8);
                const f16x8 nv = *(const f16x8*)(nbase + (size_t)s * 2048);
                const f16x2 h0 = PAIR(hv, 0), h1 = PAIR(hv, 2),
                            h2 = PAIR(hv, 4), h3 = PAIR(hv, 6);
                ar = fdot2_(PAIR(rw[s], 0), h0, ar);
                ar = fdot2_(PAIR(rw[s], 2), h1, ar);
                ar = fdot2_(PAIR(rw[s], 4), h2, ar);
                ar = fdot2_(PAIR(rw[s], 6), h3, ar);
                az = fdot2_(PAIR(zw[s], 0), h0, az);
                az = fdot2_(PAIR(zw[s], 2), h1, az);
                az = fdot2_(PAIR(zw[s], 4), h2, az);
                az = fdot2_(PAIR(zw[s], 6), h3, az);
                an = fdot2_(PAIR(nv, 0), h0, an);
                an = fdot2_(PAIR(nv, 2), h1, an);
                an = fdot2_(PAIR(nv, 4), h2, an);
                an = fdot2_(PAIR(nv, 6), h3, an);
            }
            ar += __shfl_xor(ar, 1);
            az += __shfl_xor(az, 1);
            an += __shfl_xor(an, 1);
            const float r = sigmoidf_(xr + ar + bhr);
            const float z = sigmoidf_(xz + az + bhz);
            const float n = tanhf_(xn + r * (an + bhn));
            const float hnew = (1.f - z) * n + z * hprev;
            hprev = hnew;
            if (c == 0) {
                hb[cur ^ 1][jpad] = (f16)hnew;
                if (t == i) Hc[((size_t)i * NB + b) * NH + j] = hnew;
            }
            cur ^= 1;
            __syncthreads();
        }
    }
}

// ---------------- Phase 2: lockstep re-run of all prefix chains + fused attention.
// Grid: 32 b x 8 bk; each WG owns 16 chains i = bk + 8u, 512 threads:
// col = tid>>1 (0..255), c = tid&1 (128-wide k-half). 8 waves = 2 waves/SIMD.
__global__ __attribute__((amdgpu_waves_per_eu(2, 2))) __launch_bounds__(512)
void k_attn(
    const float* __restrict__ Hc, const float* __restrict__ xw,
    const float* __restrict__ uax, const float* __restrict__ xp,
    const f16x8* __restrict__ Wpk, const f16x8* __restrict__ Wak,
    const float* __restrict__ bhh, const float* __restrict__ ba,
    const float* __restrict__ va_w, const float* __restrict__ Wo,
    const float* __restrict__ bo, float* __restrict__ out) {
    const int b  = blockIdx.x >> 3;
    const int bk = blockIdx.x & 7;
    const int tid = threadIdx.x;
    const int col = tid >> 1, c = tid & 1;
    const int lane = tid & 63, wid = tid >> 6;

    __shared__ __align__(16) float S[16][NH];
    __shared__ __align__(16) f16 Sh[16][NH];
    __shared__ float red1[8][16];
    __shared__ float mL[16], lL[16], aL[16], eL[16];
    __shared__ float redH[8][256];

    const float bhr = bhh[col], bhz = bhh[NH + col], bhn = bhh[2 * NH + col];
    const float ba_j = ba[col], va_j = va_w[col];
    float ctx[16];
#pragma unroll
    for (int u = 0; u < 16; ++u) {
        const int ic = bk + 8 * u;
        const float hv = (ic == 0) ? 0.f : Hc[((size_t)(ic - 1) * NB + b) * NH + col];
        if (c == 0) { S[u][col] = hv; Sh[u][col] = (f16)hv; }
        ctx[u] = 0.f;
    }
    if (tid < 16) { mL[tid] = -1e30f; lL[tid] = 0.f; }
    __syncthreads();

    const int imax = bk + 8 * 15;
#pragma unroll 1
    for (int t = 0; t <= imax; ++t) {
        const size_t base = (size_t)(t * NB + b);
        const float xr = xw[base * 3 * NH + col];
        const float xz = xw[base * 3 * NH + NH + col];
        const float xn = xw[base * 3 * NH + 2 * NH + col];
        const float ux = uax[base * NH + col];
        const float xpt = xp[base * NH + col];

        // ---- GRU matvec for active chains (i >= t); k-half per c
        float ar[16], az[16], an[16];
#pragma unroll
        for (int u = 0; u < 16; ++u) { ar[u] = 0.f; az[u] = 0.f; an[u] = 0.f; }
#pragma unroll 2
        for (int kk = 0; kk < 16; ++kk) {
            const int kc = kk * 2 + c;
            const f16x8 wR = Wpk[kc * 768 + col];
            const f16x8 wZ = Wpk[kc * 768 + 256 + col];
            const f16x8 wN = Wpk[kc * 768 + 512 + col];
#pragma unroll
            for (int u = 0; u < 16; ++u) {
                if (bk + 8 * u < t) continue;      // frozen chain (uniform branch)
                const f16x8 hv = *(const f16x8*)&Sh[u][kc * 8];
                const f16x2 h0 = PAIR(hv, 0), h1 = PAIR(hv, 2),
                            h2 = PAIR(hv, 4), h3 = PAIR(hv, 6);
                ar[u] = fdot2_(PAIR(wR, 0), h0, ar[u]);
                ar[u] = fdot2_(PAIR(wR, 2), h1, ar[u]);
                ar[u] = fdot2_(PAIR(wR, 4), h2, ar[u]);
                ar[u] = fdot2_(PAIR(wR, 6), h3, ar[u]);
                az[u] = fdot2_(PAIR(wZ, 0), h0, az[u]);
                az[u] = fdot2_(PAIR(wZ, 2), h1, az[u]);
                az[u] = fdot2_(PAIR(wZ, 4), h2, az[u]);
                az[u] = fdot2_(PAIR(wZ, 6), h3, az[u]);
                an[u] = fdot2_(PAIR(wN, 0), h0, an[u]);
                an[u] = fdot2_(PAIR(wN, 2), h1, an[u]);
                an[u] = fdot2_(PAIR(wN, 4), h2, an[u]);
                an[u] = fdot2_(PAIR(wN, 6), h3, an[u]);
            }
        }
        float hn[16];
#pragma unroll
        for (int u = 0; u < 16; ++u) {
            if (bk + 8 * u < t) continue;
            float arf = ar[u] + __shfl_xor(ar[u], 1);
            float azf = az[u] + __shfl_xor(az[u], 1);
            float anf = an[u] + __shfl_xor(an[u], 1);
            const float r = sigmoidf_(xr + arf + bhr);
            const float z = sigmoidf_(xz + azf + bhz);
            const float n = tanhf_(xn + r * (anf + bhn));
            hn[u] = (1.f - z) * n + z * S[u][col];
        }
        __syncthreads();                      // all Sh reads of this step done
#pragma unroll
        for (int u = 0; u < 16; ++u) {
            if (bk + 8 * u < t) continue;
            if (c == 0) { S[u][col] = hn[u]; Sh[u][col] = (f16)hn[u]; }
        }
        __syncthreads();                      // Sh now holds outs[t]

        // ---- attention scores for active chains
        float sc[16];
#pragma unroll
        for (int u = 0; u < 16; ++u) sc[u] = 0.f;
#pragma unroll 2
        for (int kk = 0; kk < 16; ++kk) {
            const int kc = kk * 2 + c;
            const f16x8 wA = Wak[kc * 256 + col];
#pragma unroll
            for (int u = 0; u < 16; ++u) {
                if (bk + 8 * u < t) continue;
                const f16x8 hv = *(const f16x8*)&Sh[u][kc * 8];
                sc[u] = fdot2_(PAIR(wA, 0), PAIR(hv, 0), sc[u]);
                sc[u] = fdot2_(PAIR(wA, 2), PAIR(hv, 2), sc[u]);
                sc[u] = fdot2_(PAIR(wA, 4), PAIR(hv, 4), sc[u]);
                sc[u] = fdot2_(PAIR(wA, 6), PAIR(hv, 6), sc[u]);
            }
        }
#pragma unroll
        for (int u = 0; u < 16; ++u) {
            if (bk + 8 * u < t) continue;
            const float sv = sc[u] + __shfl_xor(sc[u], 1);   // full-k (Wa h)[col]
            float p = (c == 0) ? va_j * tanhf_(sv + ba_j + ux) : 0.f;
#pragma unroll
            for (int off = 32; off; off >>= 1) p += __shfl_xor(p, off);
            if (lane == 0) red1[wid][u] = p;
        }
        __syncthreads();
        if (tid < 16 && bk + 8 * tid >= t) {   // online softmax state per chain
            float s = 0.f;
#pragma unroll
            for (int w = 0; w < 8; ++w) s += red1[w][tid];
            const float mo = mL[tid];
            const float mn = fmaxf(mo, s);
            const float e  = __expf(s - mn);
            const float al = __expf(mo - mn);
            lL[tid] = lL[tid] * al + e;
            mL[tid] = mn; aL[tid] = al; eL[tid] = e;
        }
        __syncthreads();
#pragma unroll
        for (int u = 0; u < 16; ++u) {
            if (bk + 8 * u < t) continue;
            ctx[u] = ctx[u] * aL[u] + eL[u] * xpt;
        }
    }

    // ---- output head per chain: logits = [h_last, context] @ Wo^T + bo
#pragma unroll 1
    for (int u = 0; u < 16; ++u) {
        const float hl = S[u][col];           // final state == h_last(i)
        const float cx = ctx[u] / lL[u];
#pragma unroll
        for (int cls = 0; cls < NC; ++cls) {
            float p = Wo[cls * (2 * NH) + col] * hl + Wo[cls * (2 * NH) + NH + col] * cx;
            p = (c == 0) ? p : 0.f;
#pragma unroll
            for (int off = 32; off; off >>= 1) p += __shfl_xor(p, off);
            if (lane == 0) redH[wid][u * 16 + cls] = p;
        }
    }
    __syncthreads();
    if (tid < 256) {
        const int u = tid >> 4, cls = tid & 15;
        const int ic = bk + 8 * u;
        float lg = bo[cls];
#pragma unroll
        for (int w = 0; w < 8; ++w) lg += redH[w][tid];
        out[((size_t)b * NT + ic) * NC + cls] = sigmoidf_(lg);
    }
}

extern "C" void kernel_launch(void* const* d_in, const int* in_sizes, int n_in,
                              void* d_out, int out_size, void* d_ws, size_t ws_size,
                              hipStream_t stream) {
    (void)in_sizes; (void)n_in; (void)out_size; (void)ws_size;
    const float* x    = (const float*)d_in[0];
    const float* W_in = (const float*)d_in[1];
    const float* b_in = (const float*)d_in[2];
    const float* Wih  = (const float*)d_in[3];
    const float* bih  = (const float*)d_in[4];
    const float* Whh  = (const float*)d_in[5];
    const float* bhh  = (const float*)d_in[6];
    const float* Wa   = (const float*)d_in[7];
    const float* ba   = (const float*)d_in[8];
    const float* Ua   = (const float*)d_in[9];
    const float* ub   = (const float*)d_in[10];
    const float* va_w = (const float*)d_in[11];
    // d_in[12] = va_b: cancels in softmax
    const float* Wo   = (const float*)d_in[13];
    const float* bo   = (const float*)d_in[14];
    float* out = (float*)d_out;

    float* ws  = (float*)d_ws;
    float* xp  = ws;                                    // NT*NB*NH        (4 MB)
    float* xw  = xp  + (size_t)NT * NB * NH;            // NT*NB*3NH       (12.6 MB)
    float* uax = xw  + (size_t)NT * NB * 3 * NH;        // NT*NB*NH        (4 MB)
    float* Hc  = uax + (size_t)NT * NB * NH;            // NT*NB*NH        (4 MB)
    f16x8* Wpk = (f16x8*)(Hc + (size_t)NT * NB * NH);   // 32*768 f16x8    (384 KB)
    f16x8* Wak = Wpk + 32 * 768;                        // 32*256 f16x8    (128 KB)

    hipLaunchKernelGGL(k_lin_in, dim3(NT * NB), dim3(256), 0, stream, x, W_in, b_in, xp);
    hipLaunchKernelGGL(k_proj,   dim3(NT * NB), dim3(256), 0, stream, xp, Wih, bih, Ua, ub, xw, uax);
    hipLaunchKernelGGL(k_pack,   dim3(128),     dim3(256), 0, stream, Whh, Wa, Wpk, Wak);
    hipLaunchKernelGGL(k_chain,  dim3(NB),      dim3(512), 0, stream, Wpk, bhh, xw, Hc);
    hipLaunchKernelGGL(k_attn,   dim3(NB * 8),  dim3(512), 0, stream,
                       Hc, xw, uax, xp, Wpk, Wak, bhh, ba, va_w, Wo, bo, out);
}

// Round 8
// 14621.440 us; speedup vs baseline: 3.4142x; 1.0218x over previous
//
#include <hip/hip_runtime.h>

constexpr int NB = 32;    // batch
constexpr int NT = 128;   // time
constexpr int NE = 256;   // embed
constexpr int NH = 256;   // hidden
constexpr int NC = 16;    // classes

typedef _Float16 f16;
typedef f16 f16x2 __attribute__((ext_vector_type(2)));
typedef f16 f16x8 __attribute__((ext_vector_type(8)));

__device__ __forceinline__ float sigmoidf_(float x) {
    return 1.f / (1.f + __expf(-x));
}
__device__ __forceinline__ float tanhf_(float x) {
    x = fminf(fmaxf(x, -15.f), 15.f);
    float e = __expf(-2.f * x);
    return (1.f - e) / (1.f + e);
}
__device__ __forceinline__ float dot4_(float4 a, float4 b) {
    return a.x * b.x + a.y * b.y + a.z * b.z + a.w * b.w;
}
#if __has_builtin(__builtin_amdgcn_fdot2)
__device__ __forceinline__ float fdot2_(f16x2 a, f16x2 b, float c) {
    return __builtin_amdgcn_fdot2(a, b, c, false);
}
#else
__device__ __forceinline__ float fdot2_(f16x2 a, f16x2 b, float c) {
    return (float)a[0] * (float)b[0] + (float)a[1] * (float)b[1] + c;
}
#endif
#define PAIR(v, k) __builtin_shufflevector((v), (v), (k), (k) + 1)

// ---------------- Prologue 1: xp[t][b][j] = x[b][t][:] . W_in[j][:] + b_in[j]
__global__ __launch_bounds__(256) void k_lin_in(
    const float* __restrict__ x, const float* __restrict__ W_in,
    const float* __restrict__ b_in, float* __restrict__ xp) {
    const int tb = blockIdx.x;           // t*NB + b
    const int t = tb >> 5, b = tb & 31;
    const int tid = threadIdx.x;
    __shared__ __align__(16) float xl[NE];
    xl[tid] = x[(b * NT + t) * NE + tid];
    __syncthreads();
    const float* __restrict__ wr = W_in + tid * NE;
    float acc = b_in[tid];
#pragma unroll 8
    for (int k = 0; k < NE; k += 4)
        acc += dot4_(*(const float4*)(wr + k), *(const float4*)(xl + k));
    xp[tb * NH + tid] = acc;
}

// ---------------- Prologue 2: xw = xp.Wih^T + bih ; uax = xp.Ua^T + ub
__global__ __launch_bounds__(256) void k_proj(
    const float* __restrict__ xp, const float* __restrict__ Wih,
    const float* __restrict__ bih, const float* __restrict__ Ua,
    const float* __restrict__ ub, float* __restrict__ xw,
    float* __restrict__ uax) {
    const int tb = blockIdx.x;
    const int tid = threadIdx.x;
    __shared__ __align__(16) float xl[NH];
    xl[tid] = xp[tb * NH + tid];
    __syncthreads();
    const float* __restrict__ wr = Wih + tid * NH;
    const float* __restrict__ wz = Wih + (NH + tid) * NH;
    const float* __restrict__ wn = Wih + (2 * NH + tid) * NH;
    const float* __restrict__ wu = Ua + tid * NH;
    float ar = bih[tid], az = bih[NH + tid], an = bih[2 * NH + tid], au = ub[tid];
#pragma unroll 4
    for (int k = 0; k < NH; k += 4) {
        float4 xv = *(const float4*)(xl + k);
        ar += dot4_(*(const float4*)(wr + k), xv);
        az += dot4_(*(const float4*)(wz + k), xv);
        an += dot4_(*(const float4*)(wn + k), xv);
        au += dot4_(*(const float4*)(wu + k), xv);
    }
    float* xwp = xw + tb * (3 * NH);
    xwp[tid] = ar;
    xwp[NH + tid] = az;
    xwp[2 * NH + tid] = an;
    uax[tb * NH + tid] = au;
}

// ---------------- Pack Whh/Wa to f16x8 [kc][row] so loads coalesce.
__global__ __launch_bounds__(256) void k_pack(
    const float* __restrict__ Whh, const float* __restrict__ Wa,
    f16x8* __restrict__ Wpk, f16x8* __restrict__ Wak) {
    const int id = blockIdx.x * 256 + threadIdx.x;
    if (id < 32 * 768) {
        const int kc = id / 768, row = id % 768;
        const float* src = Whh + row * NH + kc * 8;
        f16x8 v;
#pragma unroll
        for (int m = 0; m < 8; ++m) v[m] = (f16)src[m];
        Wpk[id] = v;
    } else {
        const int id2 = id - 32 * 768;   // < 8192
        const int kc = id2 >> 8, row = id2 & 255;
        const float* src = Wa + row * NH + kc * 8;
        f16x8 v;
#pragma unroll
        for (int m = 0; m < 8; ++m) v[m] = (f16)src[m];
        Wak[id2] = v;
    }
}

// ---------------- Phase 1: sequential carried-hidden chain. 1 WG / batch.
// LEDGER r1-r7: the cost is per-step WEIGHT TRAFFIC (384 KB/step from
// somewhere). r2: ~205KB scratch spill (2740 cyc/step). r6: all-L2 serialized
// (8900). r7: n-gate in LDS [kc][row] -> 8 lanes/bank-quad = 1.35e8 conflicts
// (512 cyc/step) + compiler rematerialized part of rw/zw as L2 re-loads
// (VGPR=104 < 128 attempted) -> 3060 cyc/step. No config was LDS-BW-clean.
// ROUND 8: conflict-free tri-source split.
//   sW layout [slot][tid]: lane reads sW[slot*512+tid] -> contiguous 1024B
//   per wave, ZERO conflicts by construction (vs [kc][row]'s 8-way).
//   19 slots = 155.6 KB (LDS cap 160K): z s=6..15, n s=0..8.
//   Resident regs: r s=0..15 (64) + z s=0..5 (24) = 88.
//   L2 stream: n s=9..15, 7 loads issued together at step top, consumed
//   ~60 instrs later (batched; no r6 per-use serialization).
// Per-step: LDS 156KB @ 256B/cyc ~= 610 cyc, VALU 768 cyc, L2 57KB ~430 cyc
// -> overlapped step ~1300-1700 cyc vs 3060 now.
__global__ __launch_bounds__(512) void k_chain(
    const f16x8* __restrict__ Wpk, const float* __restrict__ bhh,
    const float* __restrict__ xw, float* __restrict__ Hc) {
    const int b = blockIdx.x;
    const int tid = threadIdx.x;
    const int j = tid >> 1, c = tid & 1;

    __shared__ __align__(16) f16x8 sW[19 * 512];   // 155648 B, [slot][tid]
    __shared__ __align__(16) f16 hb[2][272];       // padded (r4: conflict-free)

    // stage streamed chunks: slot 0..9 = z gate s=6..15; slot 10..18 = n s=0..8
#pragma unroll
    for (int idx = 0; idx < 19; ++idx) {
        const int s = (idx < 10) ? (6 + idx) : (idx - 10);
        const int goff = (idx < 10) ? 256 : 512;
        sW[idx * 512 + tid] = Wpk[(size_t)(c * 16 + s) * 768 + goff + j];
    }

    // resident weights: full r gate + z s=0..5  (88 VGPRs)
    f16x8 rw[16], zw[6];
    const f16x8* __restrict__ wb = Wpk + (size_t)(c * 16) * 768 + j;
#pragma unroll
    for (int s = 0; s < 16; ++s) rw[s] = wb[(size_t)s * 768];
#pragma unroll
    for (int s = 0; s < 6; ++s) zw[s] = wb[(size_t)s * 768 + 256];

    const float bhr = bhh[j], bhz = bhh[NH + j], bhn = bhh[2 * NH + j];
    if (tid < NH) hb[0][(tid < 128) ? tid : 136 + (tid - 128)] = (f16)0.f;
    float hprev = 0.f;
    int cur = 0;
    const int jpad = (j < 128) ? j : 136 + (j - 128);
    __syncthreads();

#pragma unroll 1
    for (int i = 0; i < NT; ++i) {
#pragma unroll 1
        for (int t = 0; t <= i; ++t) {
            // L2-streamed n-gate chunks s=9..15: issue all 7 together now,
            // consumed at the tail of the dot loop (~60 instrs away).
            f16x8 ng[7];
#pragma unroll
            for (int q = 0; q < 7; ++q)
                ng[q] = wb[(size_t)(9 + q) * 768 + 512];

            // xw row for this step (L2; consumed after the dot loop)
            const float* __restrict__ xwp = xw + (size_t)(t * NB + b) * (3 * NH);
            const float xr = xwp[j], xz = xwp[NH + j], xn = xwp[2 * NH + j];

            const f16* hc = hb[cur] + c * 136;
            float ar = 0.f, az = 0.f, an = 0.f;
#pragma unroll
            for (int s = 0; s < 16; ++s) {
                const f16x8 hv = *(const f16x8*)(hc + s * 8);
                const f16x8 wZ = (s < 6) ? zw[s] : sW[(s - 6) * 512 + tid];
                const f16x8 wN = (s < 9) ? sW[(10 + s) * 512 + tid] : ng[s - 9];
                const f16x2 h0 = PAIR(hv, 0), h1 = PAIR(hv, 2),
                            h2 = PAIR(hv, 4), h3 = PAIR(hv, 6);
                ar = fdot2_(PAIR(rw[s], 0), h0, ar);
                ar = fdot2_(PAIR(rw[s], 2), h1, ar);
                ar = fdot2_(PAIR(rw[s], 4), h2, ar);
                ar = fdot2_(PAIR(rw[s], 6), h3, ar);
                az = fdot2_(PAIR(wZ, 0), h0, az);
                az = fdot2_(PAIR(wZ, 2), h1, az);
                az = fdot2_(PAIR(wZ, 4), h2, az);
                az = fdot2_(PAIR(wZ, 6), h3, az);
                an = fdot2_(PAIR(wN, 0), h0, an);
                an = fdot2_(PAIR(wN, 2), h1, an);
                an = fdot2_(PAIR(wN, 4), h2, an);
                an = fdot2_(PAIR(wN, 6), h3, an);
            }
            ar += __shfl_xor(ar, 1);
            az += __shfl_xor(az, 1);
            an += __shfl_xor(an, 1);
            const float r = sigmoidf_(xr + ar + bhr);
            const float z = sigmoidf_(xz + az + bhz);
            const float n = tanhf_(xn + r * (an + bhn));
            const float hnew = (1.f - z) * n + z * hprev;
            hprev = hnew;
            if (c == 0) {
                hb[cur ^ 1][jpad] = (f16)hnew;
                if (t == i) Hc[((size_t)i * NB + b) * NH + j] = hnew;
            }
            cur ^= 1;
            __syncthreads();
        }
    }
}

// ---------------- Phase 2: lockstep re-run of all prefix chains + fused attention.
// Grid: 32 b x 8 bk; each WG owns 16 chains i = bk + 8u, 512 threads:
// col = tid>>1 (0..255), c = tid&1 (128-wide k-half). 8 waves = 2 waves/SIMD.
__global__ __attribute__((amdgpu_waves_per_eu(2, 2))) __launch_bounds__(512)
void k_attn(
    const float* __restrict__ Hc, const float* __restrict__ xw,
    const float* __restrict__ uax, const float* __restrict__ xp,
    const f16x8* __restrict__ Wpk, const f16x8* __restrict__ Wak,
    const float* __restrict__ bhh, const float* __restrict__ ba,
    const float* __restrict__ va_w, const float* __restrict__ Wo,
    const float* __restrict__ bo, float* __restrict__ out) {
    const int b  = blockIdx.x >> 3;
    const int bk = blockIdx.x & 7;
    const int tid = threadIdx.x;
    const int col = tid >> 1, c = tid & 1;
    const int lane = tid & 63, wid = tid >> 6;

    __shared__ __align__(16) float S[16][NH];
    __shared__ __align__(16) f16 Sh[16][NH];
    __shared__ float red1[8][16];
    __shared__ float mL[16], lL[16], aL[16], eL[16];
    __shared__ float redH[8][256];

    const float bhr = bhh[col], bhz = bhh[NH + col], bhn = bhh[2 * NH + col];
    const float ba_j = ba[col], va_j = va_w[col];
    float ctx[16];
#pragma unroll
    for (int u = 0; u < 16; ++u) {
        const int ic = bk + 8 * u;
        const float hv = (ic == 0) ? 0.f : Hc[((size_t)(ic - 1) * NB + b) * NH + col];
        if (c == 0) { S[u][col] = hv; Sh[u][col] = (f16)hv; }
        ctx[u] = 0.f;
    }
    if (tid < 16) { mL[tid] = -1e30f; lL[tid] = 0.f; }
    __syncthreads();

    const int imax = bk + 8 * 15;
#pragma unroll 1
    for (int t = 0; t <= imax; ++t) {
        const size_t base = (size_t)(t * NB + b);
        const float xr = xw[base * 3 * NH + col];
        const float xz = xw[base * 3 * NH + NH + col];
        const float xn = xw[base * 3 * NH + 2 * NH + col];
        const float ux = uax[base * NH + col];
        const float xpt = xp[base * NH + col];

        // ---- GRU matvec for active chains (i >= t); k-half per c
        float ar[16], az[16], an[16];
#pragma unroll
        for (int u = 0; u < 16; ++u) { ar[u] = 0.f; az[u] = 0.f; an[u] = 0.f; }
#pragma unroll 2
        for (int kk = 0; kk < 16; ++kk) {
            const int kc = kk * 2 + c;
            const f16x8 wR = Wpk[kc * 768 + col];
            const f16x8 wZ = Wpk[kc * 768 + 256 + col];
            const f16x8 wN = Wpk[kc * 768 + 512 + col];
#pragma unroll
            for (int u = 0; u < 16; ++u) {
                if (bk + 8 * u < t) continue;      // frozen chain (uniform branch)
                const f16x8 hv = *(const f16x8*)&Sh[u][kc * 8];
                const f16x2 h0 = PAIR(hv, 0), h1 = PAIR(hv, 2),
                            h2 = PAIR(hv, 4), h3 = PAIR(hv, 6);
                ar[u] = fdot2_(PAIR(wR, 0), h0, ar[u]);
                ar[u] = fdot2_(PAIR(wR, 2), h1, ar[u]);
                ar[u] = fdot2_(PAIR(wR, 4), h2, ar[u]);
                ar[u] = fdot2_(PAIR(wR, 6), h3, ar[u]);
                az[u] = fdot2_(PAIR(wZ, 0), h0, az[u]);
                az[u] = fdot2_(PAIR(wZ, 2), h1, az[u]);
                az[u] = fdot2_(PAIR(wZ, 4), h2, az[u]);
                az[u] = fdot2_(PAIR(wZ, 6), h3, az[u]);
                an[u] = fdot2_(PAIR(wN, 0), h0, an[u]);
                an[u] = fdot2_(PAIR(wN, 2), h1, an[u]);
                an[u] = fdot2_(PAIR(wN, 4), h2, an[u]);
                an[u] = fdot2_(PAIR(wN, 6), h3, an[u]);
            }
        }
        float hn[16];
#pragma unroll
        for (int u = 0; u < 16; ++u) {
            if (bk + 8 * u < t) continue;
            float arf = ar[u] + __shfl_xor(ar[u], 1);
            float azf = az[u] + __shfl_xor(az[u], 1);
            float anf = an[u] + __shfl_xor(an[u], 1);
            const float r = sigmoidf_(xr + arf + bhr);
            const float z = sigmoidf_(xz + azf + bhz);
            const float n = tanhf_(xn + r * (anf + bhn));
            hn[u] = (1.f - z) * n + z * S[u][col];
        }
        __syncthreads();                      // all Sh reads of this step done
#pragma unroll
        for (int u = 0; u < 16; ++u) {
            if (bk + 8 * u < t) continue;
            if (c == 0) { S[u][col] = hn[u]; Sh[u][col] = (f16)hn[u]; }
        }
        __syncthreads();                      // Sh now holds outs[t]

        // ---- attention scores for active chains
        float sc[16];
#pragma unroll
        for (int u = 0; u < 16; ++u) sc[u] = 0.f;
#pragma unroll 2
        for (int kk = 0; kk < 16; ++kk) {
            const int kc = kk * 2 + c;
            const f16x8 wA = Wak[kc * 256 + col];
#pragma unroll
            for (int u = 0; u < 16; ++u) {
                if (bk + 8 * u < t) continue;
                const f16x8 hv = *(const f16x8*)&Sh[u][kc * 8];
                sc[u] = fdot2_(PAIR(wA, 0), PAIR(hv, 0), sc[u]);
                sc[u] = fdot2_(PAIR(wA, 2), PAIR(hv, 2), sc[u]);
                sc[u] = fdot2_(PAIR(wA, 4), PAIR(hv, 4), sc[u]);
                sc[u] = fdot2_(PAIR(wA, 6), PAIR(hv, 6), sc[u]);
            }
        }
#pragma unroll
        for (int u = 0; u < 16; ++u) {
            if (bk + 8 * u < t) continue;
            const float sv = sc[u] + __shfl_xor(sc[u], 1);   // full-k (Wa h)[col]
            float p = (c == 0) ? va_j * tanhf_(sv + ba_j + ux) : 0.f;
#pragma unroll
            for (int off = 32; off; off >>= 1) p += __shfl_xor(p, off);
            if (lane == 0) red1[wid][u] = p;
        }
        __syncthreads();
        if (tid < 16 && bk + 8 * tid >= t) {   // online softmax state per chain
            float s = 0.f;
#pragma unroll
            for (int w = 0; w < 8; ++w) s += red1[w][tid];
            const float mo = mL[tid];
            const float mn = fmaxf(mo, s);
            const float e  = __expf(s - mn);
            const float al = __expf(mo - mn);
            lL[tid] = lL[tid] * al + e;
            mL[tid] = mn; aL[tid] = al; eL[tid] = e;
        }
        __syncthreads();
#pragma unroll
        for (int u = 0; u < 16; ++u) {
            if (bk + 8 * u < t) continue;
            ctx[u] = ctx[u] * aL[u] + eL[u] * xpt;
        }
    }

    // ---- output head per chain: logits = [h_last, context] @ Wo^T + bo
#pragma unroll 1
    for (int u = 0; u < 16; ++u) {
        const float hl = S[u][col];           // final state == h_last(i)
        const float cx = ctx[u] / lL[u];
#pragma unroll
        for (int cls = 0; cls < NC; ++cls) {
            float p = Wo[cls * (2 * NH) + col] * hl + Wo[cls * (2 * NH) + NH + col] * cx;
            p = (c == 0) ? p : 0.f;
#pragma unroll
            for (int off = 32; off; off >>= 1) p += __shfl_xor(p, off);
            if (lane == 0) redH[wid][u * 16 + cls] = p;
        }
    }
    __syncthreads();
    if (tid < 256) {
        const int u = tid >> 4, cls = tid & 15;
        const int ic = bk + 8 * u;
        float lg = bo[cls];
#pragma unroll
        for (int w = 0; w < 8; ++w) lg += redH[w][tid];
        out[((size_t)b * NT + ic) * NC + cls] = sigmoidf_(lg);
    }
}

extern "C" void kernel_launch(void* const* d_in, const int* in_sizes, int n_in,
                              void* d_out, int out_size, void* d_ws, size_t ws_size,
                              hipStream_t stream) {
    (void)in_sizes; (void)n_in; (void)out_size; (void)ws_size;
    const float* x    = (const float*)d_in[0];
    const float* W_in = (const float*)d_in[1];
    const float* b_in = (const float*)d_in[2];
    const float* Wih  = (const float*)d_in[3];
    const float* bih  = (const float*)d_in[4];
    const float* Whh  = (const float*)d_in[5];
    const float* bhh  = (const float*)d_in[6];
    const float* Wa   = (const float*)d_in[7];
    const float* ba   = (const float*)d_in[8];
    const float* Ua   = (const float*)d_in[9];
    const float* ub   = (const float*)d_in[10];
    const float* va_w = (const float*)d_in[11];
    // d_in[12] = va_b: cancels in softmax
    const float* Wo   = (const float*)d_in[13];
    const float* bo   = (const float*)d_in[14];
    float* out = (float*)d_out;

    float* ws  = (float*)d_ws;
    float* xp  = ws;                                    // NT*NB*NH        (4 MB)
    float* xw  = xp  + (size_t)NT * NB * NH;            // NT*NB*3NH       (12.6 MB)
    float* uax = xw  + (size_t)NT * NB * 3 * NH;        // NT*NB*NH        (4 MB)
    float* Hc  = uax + (size_t)NT * NB * NH;            // NT*NB*NH        (4 MB)
    f16x8* Wpk = (f16x8*)(Hc + (size_t)NT * NB * NH);   // 32*768 f16x8    (384 KB)
    f16x8* Wak = Wpk + 32 * 768;                        // 32*256 f16x8    (128 KB)

    hipLaunchKernelGGL(k_lin_in, dim3(NT * NB), dim3(256), 0, stream, x, W_in, b_in, xp);
    hipLaunchKernelGGL(k_proj,   dim3(NT * NB), dim3(256), 0, stream, xp, Wih, bih, Ua, ub, xw, uax);
    hipLaunchKernelGGL(k_pack,   dim3(128),     dim3(256), 0, stream, Whh, Wa, Wpk, Wak);
    hipLaunchKernelGGL(k_chain,  dim3(NB),      dim3(512), 0, stream, Wpk, bhh, xw, Hc);
    hipLaunchKernelGGL(k_attn,   dim3(NB * 8),  dim3(512), 0, stream,
                       Hc, xw, uax, xp, Wpk, Wak, bhh, ba, va_w, Wo, bo, out);
}